// Round 15
// baseline (222.624 us; speedup 1.0000x reference)
//
#include <hip/hip_runtime.h>

#define T_TOKENS 16384
#define DIM 2048
#define NE 8
#define QOUT 2048
#define LSCALE 2.0f

typedef __attribute__((ext_vector_type(4))) float f32x4;
typedef __attribute__((ext_vector_type(8))) short s16x8;
typedef __attribute__((ext_vector_type(4))) short s16x4;

__device__ __forceinline__ short f2bf(float f) {
  unsigned u = __builtin_bit_cast(unsigned, f);
  u += 0x7fffu + ((u >> 16) & 1u);   // round-to-nearest-even
  return (short)(u >> 16);
}

__device__ __forceinline__ void barrier_lds() {
  asm volatile("s_waitcnt lgkmcnt(0)" ::: "memory");
  __builtin_amdgcn_s_barrier();
}

// ---------------------------------------------------------------------------
// Pack LoRA weights (f32) into bf16 MFMA-fragment layout.
// lora_a [E][D][R]  -> P1[d8][col=e*16+r][j]  (d = d8*8+j), col in [0,128)
// lora_b [E][R][QO] -> P2[k8][c][j]           (k = k8*8+j = e*16+r)
// ---------------------------------------------------------------------------
__global__ __launch_bounds__(256) void k_pack(
    const float* __restrict__ qa, const float* __restrict__ qb,
    const float* __restrict__ va, const float* __restrict__ vb,
    short* __restrict__ Bq1, short* __restrict__ Bv1,
    short* __restrict__ Bq2, short* __restrict__ Bv2) {
  int tid = blockIdx.x * 256 + threadIdx.x;  // 131072 threads
  if (tid < 65536) {
    int mat = tid >> 15;
    int idx = tid & 32767;          // d8*128 + col
    int d8 = idx >> 7, c = idx & 127;
    int e = c >> 4, r = c & 15;
    const float* src = mat ? va : qa;
    short* dst = mat ? Bv1 : Bq1;
    s16x8 v;
#pragma unroll
    for (int j = 0; j < 8; ++j)
      v[j] = f2bf(src[((size_t)e * DIM + d8 * 8 + j) * 16 + r]);
    *(s16x8*)(dst + (size_t)idx * 8) = v;
  } else {
    int t2 = tid - 65536;
    int mat = t2 >> 15;
    int idx = t2 & 32767;           // k8*2048 + c
    int k8 = idx >> 11, c = idx & 2047;
    const float* src = mat ? vb : qb;
    short* dst = mat ? Bv2 : Bq2;
    s16x8 v;
#pragma unroll
    for (int j = 0; j < 8; ++j)
      v[j] = f2bf(src[(size_t)(k8 * 8 + j) * QOUT + c]);
    *(s16x8*)(dst + (size_t)idx * 8) = v;
  }
}

// ---------------------------------------------------------------------------
// Fused, split by output matrix m (grid.y): routing + stage1(m) + stage2(m).
// R15 occupancy fix: R8-R14 all launched <=4096 waves vs 8192 CU slots ->
// occupancy hard-capped at 50% (observed 37-40% everywhere) -> all pipes
// idle.  This config: grid (T/32, 2) x 512 thr = 8192 waves = 100% of
// slots; LDS 18.5 KB (8 blocks/CU possible); register diet targets >=6
// waves/SIMD (no phase-B prefetch/preload — TLP covers latency now).
//
// Block (x, m): tokens 32x..+31, matrix m (0=q, 1=v).
// Phase A (K=2048, BK=64): thread (r=tid>>4, kq=(tid&15)*4) stages one
// float4 of the 32x64 h tile into At (dbuf bf16); full 8-expert routing
// partials vs global rw (f32-exact, duplicated across m — cheap VALU);
// wave wv owns exactly expert wv's 16 A-cols of matrix m: 4 MFMAs/step.
// Epilogue: 16-lane shfl reduce -> per-thread softmax/top-2 -> wl ->
// scale -> low in LDS (m's 128 cols only).
// Phase B (K=128): wave wv owns out-cols [wv*256, +256) of m; per sub-tile
// (64 cols): 4 kk steps {4 B-frag loads, 2 LDS a-reads, 8 MFMA}; NT stores.
// ---------------------------------------------------------------------------
__global__ __launch_bounds__(512) void k_fused(
    const float* __restrict__ h, const float* __restrict__ rw,
    const short* __restrict__ Bq1, const short* __restrict__ Bv1,
    const short* __restrict__ Bq2, const short* __restrict__ Bv2,
    float* __restrict__ out) {
  __shared__ short At[2][32][72];   // 32 tok x 64 k bf16, 144B rows (9 KB)
  __shared__ short low[32][136];    // 32 tok x 128 cols bf16, 272B rows (8.5 KB)
  __shared__ float wl[32][NE];      // 1 KB

  const int tid = threadIdx.x;
  const int lane = tid & 63, wv = tid >> 6;
  const int lrow = lane & 15, lk = lane >> 4;
  const int row0 = blockIdx.x * 32;
  const int m = blockIdx.y;             // 0=q, 1=v
  const int r  = tid >> 4;              // 0..31: token row this thread stages
  const int kq = (tid & 15) * 4;        // k-offset within 64-wide step

  const float* hrow = h + (size_t)(row0 + r) * DIM + kq;
  const short* B1 = m ? Bv1 : Bq1;
  const int cc = wv * 16 + lrow;        // wave wv = expert wv (16 cols)

  float4 hv = *(const float4*)(hrow);   // depth-1 prefetch

  float lg[NE] = {0.f, 0.f, 0.f, 0.f, 0.f, 0.f, 0.f, 0.f};
  f32x4 acc1[2] = {};

#pragma unroll 1
  for (int kb = 0; kb < DIM; kb += 64) {
    const int cur = (kb >> 6) & 1;
    float4 hvn = *(const float4*)(hrow + ((kb + 64) & (DIM - 1)));  // dead on tail
    const int d8 = (kb >> 3) + lk;
    s16x8 bA = *(const s16x8*)(B1 + ((size_t)d8 * 128 + cc) * 8);
    s16x8 bB = *(const s16x8*)(B1 + ((size_t)(d8 + 4) * 128 + cc) * 8);
    s16x4 hb4;
    hb4[0] = f2bf(hv.x); hb4[1] = f2bf(hv.y);
    hb4[2] = f2bf(hv.z); hb4[3] = f2bf(hv.w);
    *(s16x4*)&At[cur][r][kq] = hb4;
    // routing partials (f32-exact), 2 groups of 4 to limit rv in-flight
#pragma unroll 1
    for (int g = 0; g < 2; ++g) {
#pragma unroll
      for (int e = 0; e < 4; ++e) {
        float4 rv = *(const float4*)(rw + (g * 4 + e) * DIM + kb + kq);
        lg[g * 4 + e] += hv.x * rv.x + hv.y * rv.y + hv.z * rv.z + hv.w * rv.w;
      }
    }
    barrier_lds();                       // lgkm drain only; vmcnt stays
#pragma unroll
    for (int rt = 0; rt < 2; ++rt) {
      s16x8 a0 = *(const s16x8*)&At[cur][rt * 16 + lrow][lk * 8];
      s16x8 a1 = *(const s16x8*)&At[cur][rt * 16 + lrow][32 + lk * 8];
      acc1[rt] = __builtin_amdgcn_mfma_f32_16x16x32_bf16(bA, a0, acc1[rt], 0, 0, 0);
      acc1[rt] = __builtin_amdgcn_mfma_f32_16x16x32_bf16(bB, a1, acc1[rt], 0, 0, 0);
    }
    hv = hvn;
  }

  // reduce logits across the 16 k-lanes of each token row
#pragma unroll
  for (int e = 0; e < NE; ++e) {
    lg[e] += __shfl_xor(lg[e], 1, 64);
    lg[e] += __shfl_xor(lg[e], 2, 64);
    lg[e] += __shfl_xor(lg[e], 4, 64);
    lg[e] += __shfl_xor(lg[e], 8, 64);
  }
  // softmax + top-2 (redundant across the 16 lanes of a row; deterministic)
  float mx = lg[0];
#pragma unroll
  for (int e = 1; e < NE; ++e) mx = fmaxf(mx, lg[e]);
  float p[NE], sum = 0.f;
#pragma unroll
  for (int e = 0; e < NE; ++e) { p[e] = expf(lg[e] - mx); sum += p[e]; }
  int i1 = 0; float v1 = p[0];
#pragma unroll
  for (int e = 1; e < NE; ++e) if (p[e] > v1) { v1 = p[e]; i1 = e; }
  float v2 = -1.f; int i2 = 0;
#pragma unroll
  for (int e = 0; e < NE; ++e) if (e != i1 && p[e] > v2) { v2 = p[e]; i2 = e; }
  float s1 = v1 / sum, s2 = v2 / sum;
  float dn = s1 + s2 + 1e-20f;
  float w1 = s1 / dn * LSCALE, w2 = s2 / dn * LSCALE;
  if ((tid & 15) < 8) {
    int el = tid & 7;
    wl[r][el] = (el == i1) ? w1 : ((el == i2) ? w2 : 0.f);
  }
  barrier_lds();                        // wl visible

  // scale + write low to LDS (token=lrow, cols=lk*4+j).  expert = wv.
#pragma unroll
  for (int rt = 0; rt < 2; ++rt) {
    int tok = rt * 16 + lrow;
    float wgt = wl[tok][wv];
    s16x4 v;
#pragma unroll
    for (int j = 0; j < 4; ++j) v[j] = f2bf(acc1[rt][j] * wgt);
    *(s16x4*)&low[tok][wv * 16 + lk * 4] = v;
  }
  barrier_lds();                        // low visible

  // -------------------- phase B: out[m] = low @ B2[m] --------------------
  const short* B2 = m ? Bv2 : Bq2;
  float* op = out + (size_t)m * T_TOKENS * QOUT;
  const int cwave = wv * 256;

#pragma unroll 1
  for (int sub = 0; sub < 4; ++sub) {
    const int cb = cwave + sub * 64;
    f32x4 acc[2][4] = {};
#pragma unroll
    for (int kk = 0; kk < 4; ++kk) {
      s16x8 bc[4];
#pragma unroll
      for (int ct = 0; ct < 4; ++ct) {
        int c = cb + ct * 16 + lrow;
        bc[ct] = *(const s16x8*)(B2 + ((size_t)(kk * 4 + lk) * QOUT + c) * 8);
      }
      s16x8 a0 = *(const s16x8*)&low[lrow][kk * 32 + lk * 8];
      s16x8 a1 = *(const s16x8*)&low[16 + lrow][kk * 32 + lk * 8];
#pragma unroll
      for (int ct = 0; ct < 4; ++ct) {
        acc[0][ct] = __builtin_amdgcn_mfma_f32_16x16x32_bf16(bc[ct], a0, acc[0][ct], 0, 0, 0);
        acc[1][ct] = __builtin_amdgcn_mfma_f32_16x16x32_bf16(bc[ct], a1, acc[1][ct], 0, 0, 0);
      }
    }
#pragma unroll
    for (int rt = 0; rt < 2; ++rt)
#pragma unroll
      for (int ct = 0; ct < 4; ++ct) {
        int t = row0 + rt * 16 + lrow;
        int col = cb + ct * 16 + lk * 4;
        __builtin_nontemporal_store(acc[rt][ct], (f32x4*)(op + (size_t)t * QOUT + col));
      }
  }
}

extern "C" void kernel_launch(void* const* d_in, const int* in_sizes, int n_in,
                              void* d_out, int out_size, void* d_ws, size_t ws_size,
                              hipStream_t stream) {
  const float* h  = (const float*)d_in[0];
  const float* rw = (const float*)d_in[1];
  const float* qa = (const float*)d_in[2];
  const float* qb = (const float*)d_in[3];
  const float* va = (const float*)d_in[4];
  const float* vb = (const float*)d_in[5];
  float* out = (float*)d_out;
  char* ws = (char*)d_ws;

  short* Bq1 = (short*)(ws);                    // 512 KB each
  short* Bv1 = (short*)(ws + (512 << 10));
  short* Bq2 = (short*)(ws + (1024 << 10));
  short* Bv2 = (short*)(ws + (1536 << 10));

  k_pack<<<512, 256, 0, stream>>>(qa, qb, va, vb, Bq1, Bv1, Bq2, Bv2);
  dim3 gf(T_TOKENS / 32, 2);
  k_fused<<<gf, 512, 0, stream>>>(h, rw, Bq1, Bv1, Bq2, Bv2, out);
}

// Round 16
// 201.221 us; speedup vs baseline: 1.1064x; 1.1064x over previous
//
#include <hip/hip_runtime.h>

#define T_TOKENS 16384
#define DIM 2048
#define NE 8
#define QOUT 2048
#define LSCALE 2.0f

typedef __attribute__((ext_vector_type(4))) float f32x4;
typedef __attribute__((ext_vector_type(8))) short s16x8;
typedef __attribute__((ext_vector_type(4))) short s16x4;

__device__ __forceinline__ short f2bf(float f) {
  unsigned u = __builtin_bit_cast(unsigned, f);
  u += 0x7fffu + ((u >> 16) & 1u);   // round-to-nearest-even
  return (short)(u >> 16);
}

__device__ __forceinline__ s16x8 pack8(float4 a, float4 b) {
  s16x8 r;
  r[0] = f2bf(a.x); r[1] = f2bf(a.y); r[2] = f2bf(a.z); r[3] = f2bf(a.w);
  r[4] = f2bf(b.x); r[5] = f2bf(b.y); r[6] = f2bf(b.z); r[7] = f2bf(b.w);
  return r;
}

// async global->LDS, 16B per lane.  LDS dest = wave-uniform base + lane*16.
__device__ __forceinline__ void gload16(const void* g, void* l) {
  __builtin_amdgcn_global_load_lds(
      (const __attribute__((address_space(1))) void*)g,
      (__attribute__((address_space(3))) void*)l, 16, 0, 0);
}

// ---------------------------------------------------------------------------
// Pack LoRA weights (f32) into bf16 MFMA-fragment layout.
// lora_a [E][D][R]  -> P1[d8][col=e*16+r][j]  (d = d8*8+j), col in [0,128)
// lora_b [E][R][QO] -> P2[k8][c][j]           (k = k8*8+j = e*16+r)
// ---------------------------------------------------------------------------
__global__ __launch_bounds__(256) void k_pack(
    const float* __restrict__ qa, const float* __restrict__ qb,
    const float* __restrict__ va, const float* __restrict__ vb,
    short* __restrict__ Bq1, short* __restrict__ Bv1,
    short* __restrict__ Bq2, short* __restrict__ Bv2) {
  int tid = blockIdx.x * 256 + threadIdx.x;  // 131072 threads
  if (tid < 65536) {
    int mat = tid >> 15;
    int idx = tid & 32767;          // d8*128 + col
    int d8 = idx >> 7, c = idx & 127;
    int e = c >> 4, r = c & 15;
    const float* src = mat ? va : qa;
    short* dst = mat ? Bv1 : Bq1;
    s16x8 v;
#pragma unroll
    for (int j = 0; j < 8; ++j)
      v[j] = f2bf(src[((size_t)e * DIM + d8 * 8 + j) * 16 + r]);
    *(s16x8*)(dst + (size_t)idx * 8) = v;
  } else {
    int t2 = tid - 65536;
    int mat = t2 >> 15;
    int idx = t2 & 32767;           // k8*2048 + c
    int k8 = idx >> 11, c = idx & 2047;
    const float* src = mat ? vb : qb;
    short* dst = mat ? Bv2 : Bq2;
    s16x8 v;
#pragma unroll
    for (int j = 0; j < 8; ++j)
      v[j] = f2bf(src[(size_t)(k8 * 8 + j) * QOUT + c]);
    *(s16x8*)(dst + (size_t)idx * 8) = v;
  }
}

// ---------------------------------------------------------------------------
// Routing ONLY (f32-exact, deterministic).  rw staged in LDS once per block;
// each wave owns 8 tokens sequentially.  Writes dense w[T][8] (0 for
// unselected experts, incl. top-2 renorm * SCALE).
// ---------------------------------------------------------------------------
__global__ __launch_bounds__(256) void k_prep(
    const float* __restrict__ h, const float* __restrict__ rw,
    float* __restrict__ wout) {
  __shared__ float rwl[NE * DIM];       // 64 KB
  const int tid = threadIdx.x;
  const int lane = tid & 63, wv = tid >> 6;
  {
    const float4* s = (const float4*)rw;
    float4* d = (float4*)rwl;
#pragma unroll
    for (int j = 0; j < 16; ++j) d[tid + j * 256] = s[tid + j * 256];
  }
  __syncthreads();

#pragma unroll 1
  for (int ti = 0; ti < 8; ++ti) {
    const int tok = blockIdx.x * 32 + wv * 8 + ti;
    const float* hp = h + (size_t)tok * DIM + lane * 8;
    float4 hv[8];
#pragma unroll
    for (int it = 0; it < 4; ++it) {
      hv[it * 2]     = *(const float4*)(hp + it * 512);
      hv[it * 2 + 1] = *(const float4*)(hp + it * 512 + 4);
    }
    float lg[NE];
#pragma unroll
    for (int e = 0; e < NE; ++e) {
      float acc = 0.f;
#pragma unroll
      for (int it = 0; it < 4; ++it) {
        const float* rp = rwl + e * DIM + it * 512 + lane * 8;
        float4 r0 = *(const float4*)rp, r1 = *(const float4*)(rp + 4);
        float4 a0 = hv[it * 2], a1 = hv[it * 2 + 1];
        acc += a0.x * r0.x + a0.y * r0.y + a0.z * r0.z + a0.w * r0.w
             + a1.x * r1.x + a1.y * r1.y + a1.z * r1.z + a1.w * r1.w;
      }
#pragma unroll
      for (int s = 32; s; s >>= 1) acc += __shfl_xor(acc, s, 64);
      lg[e] = acc;
    }
    float mx = lg[0];
#pragma unroll
    for (int e = 1; e < NE; ++e) mx = fmaxf(mx, lg[e]);
    float p[NE], sum = 0.f;
#pragma unroll
    for (int e = 0; e < NE; ++e) { p[e] = expf(lg[e] - mx); sum += p[e]; }
    int i1 = 0; float v1 = p[0];
#pragma unroll
    for (int e = 1; e < NE; ++e) if (p[e] > v1) { v1 = p[e]; i1 = e; }
    float v2 = -1.f; int i2 = 0;
#pragma unroll
    for (int e = 0; e < NE; ++e) if (e != i1 && p[e] > v2) { v2 = p[e]; i2 = e; }
    float s1 = v1 / sum, s2 = v2 / sum;
    float dn = s1 + s2 + 1e-20f;
    float w1 = s1 / dn * LSCALE, w2 = s2 / dn * LSCALE;
    if (lane < NE) {
      float wo = (lane == i1) ? w1 : ((lane == i2) ? w2 : 0.f);
      wout[(size_t)tok * NE + lane] = wo;
    }
  }
}

// ---------------------------------------------------------------------------
// Stage 1 as a PURE GEMM (m97 structure): low = (h @ Acat) * w.
// 256 thr (4 waves), tile 32 tok x 256 cols, grid 512 -> 2 blocks/CU.
// K-step 64, double-buffered At[2][32][64] f32 (16 KB) filled via
// global_load_lds (linear dest) with XOR-swizzled SOURCE; ds_read uses the
// same swizzle -> 2-way banks only (rule #21: both-sides-or-neither).
// f32->bf16 conversion only at fragment read (~48 VALU/step/wave).
// One barrier per K-step.  Epilogue: *w[t][e] -> bf16 low [T][128] x2.
// ---------------------------------------------------------------------------
__global__ __launch_bounds__(256) void k_s1(
    const float* __restrict__ h, const float* __restrict__ wdense,
    const short* __restrict__ Bq1, const short* __restrict__ Bv1,
    short* __restrict__ lowq, short* __restrict__ lowv) {
  __shared__ float At[2][32][64];       // 2 x 8 KB

  const int tid = threadIdx.x;
  const int lane = tid & 63, wv = tid >> 6;
  const int lrow = lane & 15, lk = lane >> 4;
  const int row0 = blockIdx.x * 32;
  const int grow = tid >> 4;            // gload row 0..15 (+16 per instr)
  const int gslot = tid & 15;           // gload 16B slot within 256B row
  const int gsw = gslot ^ grow;         // src slice swizzle (row&15 == grow)

  const short* B1 = (wv >= 2) ? Bv1 : Bq1;
  int cc[4];
#pragma unroll
  for (int ct = 0; ct < 4; ++ct) cc[ct] = (wv & 1) * 64 + ct * 16 + lrow;

  // prologue: stage tile kb=0 into buffer 0
#pragma unroll
  for (int i = 0; i < 2; ++i) {
    const float* src = h + (size_t)(row0 + i * 16 + grow) * DIM + gsw * 4;
    char* dst = (char*)&At[0][0][0] + i * 4096 + wv * 1024;
    gload16(src, dst);
  }
  __syncthreads();

  f32x4 acc[2][4] = {};

#pragma unroll 1
  for (int kb = 0; kb < DIM; kb += 64) {
    const int cur = (kb >> 6) & 1;
    const int kn = (kb + 64) & (DIM - 1);   // wraps (dead tile) on last iter
    // issue next-tile staging into buf cur^1 (completes at the barrier)
#pragma unroll
    for (int i = 0; i < 2; ++i) {
      const float* src = h + (size_t)(row0 + i * 16 + grow) * DIM + kn + gsw * 4;
      char* dst = (char*)&At[cur ^ 1][0][0] + i * 4096 + wv * 1024;
      gload16(src, dst);
    }
    // B fragments for this step (global, L2-hot)
    s16x8 b[2][4];
#pragma unroll
    for (int hf = 0; hf < 2; ++hf)
#pragma unroll
      for (int ct = 0; ct < 4; ++ct) {
        int d8 = (kb >> 3) + hf * 4 + lk;
        b[hf][ct] = *(const s16x8*)(B1 + ((size_t)d8 * 128 + cc[ct]) * 8);
      }
    // A fragments from LDS (swizzled slots), convert, MFMA
#pragma unroll
    for (int rt = 0; rt < 2; ++rt) {
      int row = rt * 16 + lrow;
      const float* base = &At[cur][row][0];
#pragma unroll
      for (int hf = 0; hf < 2; ++hf) {
        int s0 = (hf * 4 + lk) * 2;
        float4 f0 = *(const float4*)(base + ((s0 ^ lrow) * 4));
        float4 f1 = *(const float4*)(base + (((s0 + 1) ^ lrow) * 4));
        s16x8 a = pack8(f0, f1);
#pragma unroll
        for (int ct = 0; ct < 4; ++ct)
          acc[rt][ct] = __builtin_amdgcn_mfma_f32_16x16x32_bf16(b[hf][ct], a, acc[rt][ct], 0, 0, 0);
      }
    }
    __syncthreads();   // drains gload vmcnt; all waves done with buf cur
  }

  // epilogue: scale by w and store bf16 low (token=lrow axis, cols=lk*4+j)
#pragma unroll
  for (int rt = 0; rt < 2; ++rt) {
    int t = row0 + rt * 16 + lrow;
#pragma unroll
    for (int ct = 0; ct < 4; ++ct) {
      int e = (wv & 1) * 4 + ct;
      float wgt = wdense[(size_t)t * NE + e];
      int ccol = (wv & 1) * 64 + ct * 16 + lk * 4;
      short* op = (wv < 2) ? lowq : lowv;
      s16x4 v;
#pragma unroll
      for (int j = 0; j < 4; ++j) v[j] = f2bf(acc[rt][ct][j] * wgt);
      *(s16x4*)(op + (size_t)t * 128 + ccol) = v;
    }
  }
}

// ---------------------------------------------------------------------------
// Stage 2: delta = low[T,128] @ B[128,2048].  32-tok x 256-col blocks,
// grid (T/32, 16) = 8192 blocks.  K=128 = 4 unrolled MFMA steps, depth-1 B
// prefetch, nontemporal f32x4 stores.
// ---------------------------------------------------------------------------
__global__ __launch_bounds__(256) void k_up(
    const short* __restrict__ lowq, const short* __restrict__ lowv,
    const short* __restrict__ Bq2, const short* __restrict__ Bv2,
    float* __restrict__ out) {
  const int lane = threadIdx.x & 63, wv = threadIdx.x >> 6;
  const int lrow = lane & 15, lk = lane >> 4;
  const int row0 = blockIdx.x * 32;
  const int m = blockIdx.y >> 3;
  const int cb = (blockIdx.y & 7) * 256 + wv * 64;
  const short* low = m ? lowv : lowq;
  const short* B = m ? Bv2 : Bq2;
  float* op = out + (size_t)m * T_TOKENS * QOUT;

  s16x8 a[2][4];
#pragma unroll
  for (int rt = 0; rt < 2; ++rt)
#pragma unroll
    for (int kk = 0; kk < 4; ++kk)
      a[rt][kk] = *(const s16x8*)(low + (size_t)(row0 + rt * 16 + lrow) * 128 + kk * 32 + lk * 8);

  s16x8 bc[4], bn[4];
#pragma unroll
  for (int ct = 0; ct < 4; ++ct) {
    int c = cb + ct * 16 + lrow;
    bc[ct] = *(const s16x8*)(B + ((size_t)lk * QOUT + c) * 8);
  }

  f32x4 acc[2][4] = {};
#pragma unroll
  for (int kk = 0; kk < 4; ++kk) {
    const int kkn = (kk + 1) & 3;          // dead value on last iter
#pragma unroll
    for (int ct = 0; ct < 4; ++ct) {
      int c = cb + ct * 16 + lrow;
      bn[ct] = *(const s16x8*)(B + ((size_t)(kkn * 4 + lk) * QOUT + c) * 8);
    }
#pragma unroll
    for (int rt = 0; rt < 2; ++rt)
#pragma unroll
      for (int ct = 0; ct < 4; ++ct)
        acc[rt][ct] = __builtin_amdgcn_mfma_f32_16x16x32_bf16(bc[ct], a[rt][kk], acc[rt][ct], 0, 0, 0);
#pragma unroll
    for (int ct = 0; ct < 4; ++ct) bc[ct] = bn[ct];
  }
#pragma unroll
  for (int rt = 0; rt < 2; ++rt)
#pragma unroll
    for (int ct = 0; ct < 4; ++ct) {
      int t = row0 + rt * 16 + lrow;
      int col = cb + ct * 16 + lk * 4;
      __builtin_nontemporal_store(acc[rt][ct], (f32x4*)(op + (size_t)t * QOUT + col));
    }
}

extern "C" void kernel_launch(void* const* d_in, const int* in_sizes, int n_in,
                              void* d_out, int out_size, void* d_ws, size_t ws_size,
                              hipStream_t stream) {
  const float* h  = (const float*)d_in[0];
  const float* rw = (const float*)d_in[1];
  const float* qa = (const float*)d_in[2];
  const float* qb = (const float*)d_in[3];
  const float* va = (const float*)d_in[4];
  const float* vb = (const float*)d_in[5];
  float* out = (float*)d_out;
  char* ws = (char*)d_ws;

  short* Bq1 = (short*)(ws);                    // 512 KB each
  short* Bv1 = (short*)(ws + (512 << 10));
  short* Bq2 = (short*)(ws + (1024 << 10));
  short* Bv2 = (short*)(ws + (1536 << 10));
  float* wdense = (float*)(ws + (2 << 20));     // 512 KB
  short* lowq = (short*)(ws + (2560 << 10));    // 4 MB each
  short* lowv = (short*)(ws + (2560 << 10) + (4 << 20));

  k_pack<<<512, 256, 0, stream>>>(qa, qb, va, vb, Bq1, Bv1, Bq2, Bv2);
  k_prep<<<T_TOKENS / 32, 256, 0, stream>>>(h, rw, wdense);
  k_s1<<<T_TOKENS / 32, 256, 0, stream>>>(h, wdense, Bq1, Bv1, lowq, lowv);
  dim3 g2(T_TOKENS / 32, 16);
  k_up<<<g2, 256, 0, stream>>>(lowq, lowv, Bq2, Bv2, out);
}

// Round 17
// 160.790 us; speedup vs baseline: 1.3846x; 1.2514x over previous
//
#include <hip/hip_runtime.h>

#define T_TOKENS 16384
#define DIM 2048
#define NE 8
#define QOUT 2048
#define LSCALE 2.0f

typedef __attribute__((ext_vector_type(4))) float f32x4;
typedef __attribute__((ext_vector_type(8))) short s16x8;
typedef __attribute__((ext_vector_type(4))) short s16x4;

__device__ __forceinline__ short f2bf(float f) {
  unsigned u = __builtin_bit_cast(unsigned, f);
  u += 0x7fffu + ((u >> 16) & 1u);   // round-to-nearest-even
  return (short)(u >> 16);
}

__device__ __forceinline__ s16x8 pack8(float4 a, float4 b) {
  s16x8 r;
  r[0] = f2bf(a.x); r[1] = f2bf(a.y); r[2] = f2bf(a.z); r[3] = f2bf(a.w);
  r[4] = f2bf(b.x); r[5] = f2bf(b.y); r[6] = f2bf(b.z); r[7] = f2bf(b.w);
  return r;
}

__device__ __forceinline__ void gload16(const void* g, void* l) {
  __builtin_amdgcn_global_load_lds(
      (const __attribute__((address_space(1))) void*)g,
      (__attribute__((address_space(3))) void*)l, 16, 0, 0);
}

// lgkm-only barrier (LDS visibility, vmcnt stays in flight)
__device__ __forceinline__ void barrier_lds() {
  asm volatile("s_waitcnt lgkmcnt(0)" ::: "memory");
  __builtin_amdgcn_s_barrier();
}

// counted-vmcnt barrier: leave the newest 1 global_load_lds in flight
__device__ __forceinline__ void barrier_vm1() {
  asm volatile("s_waitcnt vmcnt(1) lgkmcnt(0)" ::: "memory");
  __builtin_amdgcn_s_barrier();
}

// ---------------------------------------------------------------------------
// Pack LoRA weights (f32) into bf16 MFMA-fragment layout.
// lora_a [E][D][R]  -> P1[d8][col=e*16+r][j]  (d = d8*8+j), col in [0,128)
// lora_b [E][R][QO] -> P2[k8][c][j]           (k = k8*8+j = e*16+r)
// ---------------------------------------------------------------------------
__global__ __launch_bounds__(256) void k_pack(
    const float* __restrict__ qa, const float* __restrict__ qb,
    const float* __restrict__ va, const float* __restrict__ vb,
    short* __restrict__ Bq1, short* __restrict__ Bv1,
    short* __restrict__ Bq2, short* __restrict__ Bv2) {
  int tid = blockIdx.x * 256 + threadIdx.x;  // 131072 threads
  if (tid < 65536) {
    int mat = tid >> 15;
    int idx = tid & 32767;          // d8*128 + col
    int d8 = idx >> 7, c = idx & 127;
    int e = c >> 4, r = c & 15;
    const float* src = mat ? va : qa;
    short* dst = mat ? Bv1 : Bq1;
    s16x8 v;
#pragma unroll
    for (int j = 0; j < 8; ++j)
      v[j] = f2bf(src[((size_t)e * DIM + d8 * 8 + j) * 16 + r]);
    *(s16x8*)(dst + (size_t)idx * 8) = v;
  } else {
    int t2 = tid - 65536;
    int mat = t2 >> 15;
    int idx = t2 & 32767;           // k8*2048 + c
    int k8 = idx >> 11, c = idx & 2047;
    const float* src = mat ? vb : qb;
    short* dst = mat ? Bv2 : Bq2;
    s16x8 v;
#pragma unroll
    for (int j = 0; j < 8; ++j)
      v[j] = f2bf(src[(size_t)(k8 * 8 + j) * QOUT + c]);
    *(s16x8*)(dst + (size_t)idx * 8) = v;
  }
}

// ---------------------------------------------------------------------------
// Fused: routing + stage1 (low in LDS) + stage2 (f32 out).
// = R10's best structure (140.9us) with T4 counted-vmcnt h staging:
// h goes HBM -> LDS ring (3 bufs, global_load_lds, XOR-swizzled slots) and
// is read from LDS by BOTH routing and MFMA fragments.  Step-end barrier is
// s_waitcnt vmcnt(1) (newest ring prefetch stays in flight) — never a
// vmcnt(0) drain.  Older prefetch is force-retired by this step's rv/B1
// waits (FIFO), which is free: it has had a full step of flight.
//
// Block = 32 tokens, 512 threads (8 waves), grid 512.  LDS 41.5 KB.
// Phase A (K=2048, BK=64): staging thread (g_r=tid>>4, g_s=tid&15) covers
// one 16B slot; wave wv owns concat cols [wv*32,+32) (distinct B1 frags),
// acc1[2][2]; routing = 8 experts x float4 FMAs per thread per step.
// Phase B: wave wv -> matrix m=wv>>2, cols (wv&3)*512..+511; a2 preload,
// 32 flattened iters (unroll 4), depth-1 B2 prefetch, NT stores.
// ---------------------------------------------------------------------------
__global__ __launch_bounds__(512) void k_fused(
    const float* __restrict__ h, const float* __restrict__ rw,
    const short* __restrict__ Bq1, const short* __restrict__ Bv1,
    const short* __restrict__ Bq2, const short* __restrict__ Bv2,
    float* __restrict__ out) {
  __shared__ float Ah[3][32][64];   // 24 KB ring; slot p of row r holds k-slice p^(r&15)
  __shared__ short low[32][264];    // 16.5 KB
  __shared__ float wl[32][NE];      // 1 KB

  const int tid = threadIdx.x;
  const int lane = tid & 63, wv = tid >> 6;
  const int lrow = lane & 15, lk = lane >> 4;
  const int row0 = blockIdx.x * 32;
  const int g_r = tid >> 4;             // 0..31 staging/routing row
  const int g_s = tid & 15;             // staging slot / routing kq=g_s*4
  const int psw = (g_s ^ (g_r & 15));   // physical slot this thread stages/reads

  const short* B1 = (wv >= 4) ? Bv1 : Bq1;
  int cc2[2];
#pragma unroll
  for (int ct = 0; ct < 2; ++ct) cc2[ct] = (wv & 3) * 32 + ct * 16 + lrow;

  const float* hsrc = h + (size_t)(row0 + g_r) * DIM + psw * 4;

  // prologue: stage tiles 0,1 into ring bufs 0,1
  gload16(hsrc, (char*)&Ah[0][0][0] + wv * 1024);
  gload16(hsrc + 64, (char*)&Ah[1][0][0] + wv * 1024);
  barrier_vm1();                        // tile 0 ready; tile 1 in flight

  float lg[NE] = {0.f, 0.f, 0.f, 0.f, 0.f, 0.f, 0.f, 0.f};
  f32x4 acc1[2][2] = {};
  int cur = 0, nxt = 1, nx2 = 2;

#pragma unroll 1
  for (int kb = 0; kb < DIM; kb += 64) {
    // routing: own h slice from LDS ring + global rv (L1-hot)
    float4 hv = *(const float4*)&Ah[cur][g_r][psw * 4];
#pragma unroll 1
    for (int g = 0; g < 2; ++g) {
#pragma unroll
      for (int e = 0; e < 4; ++e) {
        float4 rv = *(const float4*)(rw + (g * 4 + e) * DIM + kb + g_s * 4);
        lg[g * 4 + e] += hv.x * rv.x + hv.y * rv.y + hv.z * rv.z + hv.w * rv.w;
      }
    }
    // B1 fragments (distinct per wave; L2-hot)
    s16x8 b[2][2];
#pragma unroll
    for (int hf = 0; hf < 2; ++hf)
#pragma unroll
      for (int ct = 0; ct < 2; ++ct) {
        int d8 = (kb >> 3) + hf * 4 + lk;
        b[hf][ct] = *(const s16x8*)(B1 + ((size_t)d8 * 128 + cc2[ct]) * 8);
      }
    // A fragments from LDS ring (swizzled), convert, MFMA
#pragma unroll
    for (int rt = 0; rt < 2; ++rt) {
      const float* base = &Ah[cur][rt * 16 + lrow][0];
#pragma unroll
      for (int hf = 0; hf < 2; ++hf) {
        int s0 = hf * 8 + lk * 2;
        float4 f0 = *(const float4*)(base + ((s0 ^ lrow) * 4));
        float4 f1 = *(const float4*)(base + (((s0 + 1) ^ lrow) * 4));
        s16x8 a = pack8(f0, f1);
#pragma unroll
        for (int ct = 0; ct < 2; ++ct)
          acc1[rt][ct] = __builtin_amdgcn_mfma_f32_16x16x32_bf16(b[hf][ct], a, acc1[rt][ct], 0, 0, 0);
      }
    }
    // prefetch tile kb+128 into ring[nx2] (issued LAST -> survives barrier)
    gload16(hsrc + ((kb + 128) & (DIM - 1)), (char*)&Ah[nx2][0][0] + wv * 1024);
    barrier_vm1();                      // newest prefetch stays in flight
    int t = cur; cur = nxt; nxt = nx2; nx2 = t;
  }

  // reduce logits across the 16 k-lanes of each row (16 consecutive lanes)
#pragma unroll
  for (int e = 0; e < NE; ++e) {
    lg[e] += __shfl_xor(lg[e], 1, 64);
    lg[e] += __shfl_xor(lg[e], 2, 64);
    lg[e] += __shfl_xor(lg[e], 4, 64);
    lg[e] += __shfl_xor(lg[e], 8, 64);
  }
  // softmax + top-2 (redundant across the 16 lanes of a row; deterministic)
  float mx = lg[0];
#pragma unroll
  for (int e = 1; e < NE; ++e) mx = fmaxf(mx, lg[e]);
  float p[NE], sum = 0.f;
#pragma unroll
  for (int e = 0; e < NE; ++e) { p[e] = expf(lg[e] - mx); sum += p[e]; }
  int i1 = 0; float v1 = p[0];
#pragma unroll
  for (int e = 1; e < NE; ++e) if (p[e] > v1) { v1 = p[e]; i1 = e; }
  float v2 = -1.f; int i2 = 0;
#pragma unroll
  for (int e = 0; e < NE; ++e) if (e != i1 && p[e] > v2) { v2 = p[e]; i2 = e; }
  float s1 = v1 / sum, s2 = v2 / sum;
  float dn = s1 + s2 + 1e-20f;
  float w1 = s1 / dn * LSCALE, w2 = s2 / dn * LSCALE;
  if (g_s < 8) {
    wl[g_r][g_s] = (g_s == i1) ? w1 : ((g_s == i2) ? w2 : 0.f);
  }
  barrier_lds();                        // wl visible

  // scale + write low to LDS (token=lrow, cols=lk*4+j).  e = (wv&3)*2+ct
#pragma unroll
  for (int rt = 0; rt < 2; ++rt)
#pragma unroll
    for (int ct = 0; ct < 2; ++ct) {
      int tok = rt * 16 + lrow;
      float wgt = wl[tok][(wv & 3) * 2 + ct];
      s16x4 v;
#pragma unroll
      for (int j = 0; j < 4; ++j) v[j] = f2bf(acc1[rt][ct][j] * wgt);
      *(s16x4*)&low[tok][wv * 32 + ct * 16 + lk * 4] = v;
    }
  barrier_lds();                        // low visible

  // -------------------- phase B: out = low @ B2 --------------------
  const int m = wv >> 2;                // 0=q, 1=v
  const int cwave = (wv & 3) * 512;
  const short* B2 = m ? Bv2 : Bq2;
  float* op = out + (size_t)m * T_TOKENS * QOUT;

  s16x8 bc[4];
#pragma unroll
  for (int ct = 0; ct < 4; ++ct) {
    int c = cwave + ct * 16 + lrow;     // sub=0, kk=0 -> k8 = lk
    bc[ct] = *(const s16x8*)(B2 + ((size_t)lk * QOUT + c) * 8);
  }

  s16x8 a2[2][4];
#pragma unroll
  for (int rt = 0; rt < 2; ++rt)
#pragma unroll
    for (int kk = 0; kk < 4; ++kk)
      a2[rt][kk] = *(const s16x8*)&low[rt * 16 + lrow][m * 128 + kk * 32 + lk * 8];

  f32x4 acc[2][4] = {};
#pragma unroll 4
  for (int it = 0; it < 32; ++it) {
    const int sub = it >> 2, kk = it & 3;  // kk static under unroll 4
    const int itn = (it + 1) & 31;         // wraps (dead) on last iter
    const int subn = itn >> 2, kkn = itn & 3;
    s16x8 bn[4];
#pragma unroll
    for (int ct = 0; ct < 4; ++ct) {
      int c = cwave + subn * 64 + ct * 16 + lrow;
      bn[ct] = *(const s16x8*)(B2 + ((size_t)(kkn * 4 + lk) * QOUT + c) * 8);
    }
#pragma unroll
    for (int rt = 0; rt < 2; ++rt)
#pragma unroll
      for (int ct = 0; ct < 4; ++ct)
        acc[rt][ct] = __builtin_amdgcn_mfma_f32_16x16x32_bf16(bc[ct], a2[rt][kk], acc[rt][ct], 0, 0, 0);
    if (kk == 3) {
      int cb = cwave + sub * 64;
#pragma unroll
      for (int rt = 0; rt < 2; ++rt)
#pragma unroll
        for (int ct = 0; ct < 4; ++ct) {
          int t = row0 + rt * 16 + lrow;
          int col = cb + ct * 16 + lk * 4;
          __builtin_nontemporal_store(acc[rt][ct], (f32x4*)(op + (size_t)t * QOUT + col));
          acc[rt][ct] = (f32x4){0.f, 0.f, 0.f, 0.f};
        }
    }
#pragma unroll
    for (int ct = 0; ct < 4; ++ct) bc[ct] = bn[ct];
  }
}

extern "C" void kernel_launch(void* const* d_in, const int* in_sizes, int n_in,
                              void* d_out, int out_size, void* d_ws, size_t ws_size,
                              hipStream_t stream) {
  const float* h  = (const float*)d_in[0];
  const float* rw = (const float*)d_in[1];
  const float* qa = (const float*)d_in[2];
  const float* qb = (const float*)d_in[3];
  const float* va = (const float*)d_in[4];
  const float* vb = (const float*)d_in[5];
  float* out = (float*)d_out;
  char* ws = (char*)d_ws;

  short* Bq1 = (short*)(ws);                    // 512 KB each
  short* Bv1 = (short*)(ws + (512 << 10));
  short* Bq2 = (short*)(ws + (1024 << 10));
  short* Bv2 = (short*)(ws + (1536 << 10));

  k_pack<<<512, 256, 0, stream>>>(qa, qb, va, vb, Bq1, Bv1, Bq2, Bv2);
  k_fused<<<T_TOKENS / 32, 512, 0, stream>>>(h, rw, Bq1, Bv1, Bq2, Bv2, out);
}